// Round 14
// baseline (109.439 us; speedup 1.0000x reference)
//
#include <hip/hip_runtime.h>
#include <hip/hip_bf16.h>

#define B 2
#define C 8
#define F 256
#define W 1024
#define NH 8
#define HD 32

typedef float f32x4 __attribute__((ext_vector_type(4)));
typedef short sh8 __attribute__((ext_vector_type(8)));
typedef short sh4 __attribute__((ext_vector_type(4)));
typedef unsigned short u16;
typedef unsigned int u32;

// q pre-scale: (1/sqrt(F)) * log2(e)  so softmax uses native exp2 (v_exp_f32)
#define QSCALE 0.09016843880556021f

// native 2^x: single v_exp_f32
static __device__ __forceinline__ float fexp2(float x) {
#if __has_builtin(__builtin_amdgcn_exp2f)
  return __builtin_amdgcn_exp2f(x);
#else
  return __expf(x * 0.69314718056f);
#endif
}

// fp32 -> bf16 RNE via compiler cast
static __device__ __forceinline__ u16 f2b(float x) {
  union { __hip_bfloat16 h; u16 u; } v;
  v.h = __float2bfloat16(x);
  return v.u;
}
// 4x fp32 -> packed bf16x4 (v_cvt_pk_bf16_f32 pairs)
static __device__ __forceinline__ sh4 pack4(float p0, float p1, float p2, float p3) {
  union { __hip_bfloat162 h2[2]; sh4 s; } u;
  u.h2[0] = __float22bfloat162_rn(make_float2(p0, p1));
  u.h2[1] = __float22bfloat162_rn(make_float2(p2, p3));
  return u.s;
}
static __device__ __forceinline__ float ubits(u32 u) {
  union { u32 u; float f; } v;
  v.u = u;
  return v.f;
}

static __device__ __forceinline__ f32x4 mfma32(sh8 a, sh8 b, f32x4 c) {
  return __builtin_amdgcn_mfma_f32_16x16x32_bf16(a, b, c, 0, 0, 0);
}

static __device__ __forceinline__ f32x4 mfma16(sh4 a, sh4 b, f32x4 c) {
#if __has_builtin(__builtin_amdgcn_mfma_f32_16x16x16bf16_1k)
  return __builtin_amdgcn_mfma_f32_16x16x16bf16_1k(a, b, c, 0, 0, 0);
#else
  f32x4 d;
  asm("v_mfma_f32_16x16x16_bf16 %0, %1, %2, %3" : "=v"(d) : "v"(a), "v"(b), "v"(c));
  return d;
#endif
}

// async global->LDS, 16B/lane. g = PER-LANE source, l = wave-uniform base.
static __device__ __forceinline__ void gload16(const u16* g, u16* l, int ln) {
#if __has_builtin(__builtin_amdgcn_global_load_lds)
  __builtin_amdgcn_global_load_lds((const __attribute__((address_space(1))) void*)g,
                                   (__attribute__((address_space(3))) void*)l, 16, 0, 0);
#else
  *(sh8*)(l + ln * 8) = *(const sh8*)g;
#endif
}

// ---------------------------------------------------------------------------
// prep: fused one-time setup (x transpose / weight cvt / rope table).
// ---------------------------------------------------------------------------
__global__ __launch_bounds__(256) void prep(const float* __restrict__ x, u16* __restrict__ xt,
                                            const float* __restrict__ s0, const float* __restrict__ s1,
                                            const float* __restrict__ s2, const float* __restrict__ s3,
                                            u16* __restrict__ d0, u16* __restrict__ d1,
                                            u16* __restrict__ d2, u16* __restrict__ d3,
                                            float2* __restrict__ TAB) {
  const int bid = blockIdx.x;
  const int t = threadIdx.x;
  if (bid < 4096) {  // ---- x transpose ----
    const int bc = bid >> 8, rem = bid & 255;
    const int h0 = ((rem >> 5) & 7) * 32, w0 = (rem & 31) * 32;
    __shared__ u16 sm[32][34];
    const int a = t & 31, bql = t >> 5;
    const float* src = x + ((size_t)bc * F + h0) * W + w0;
#pragma unroll
    for (int p = 0; p < 4; ++p) {
      const int hl = bql + p * 8;
      sm[a][hl] = f2b(src[(size_t)hl * W + a]);
    }
    __syncthreads();
    u16* dst = xt + ((size_t)bc * W + w0) * F + h0;
#pragma unroll
    for (int p = 0; p < 4; ++p) {
      const int wl = bql + p * 8;
      dst[(size_t)wl * F + a] = sm[wl][a];
    }
  } else if (bid < 6144) {  // ---- weight cvt ----
    const int i = bid - 4096;
    const int which = i >> 9;
    const float* s = which == 0 ? s0 : which == 1 ? s1 : which == 2 ? s2 : s3;
    u16* d = which == 0 ? d0 : which == 1 ? d1 : which == 2 ? d2 : d3;
    const int idx = (i & 511) * 256 + t;
    const float4 v = reinterpret_cast<const float4*>(s)[idx];
    union { u16 h[4]; uint2 u; } o;
    o.h[0] = f2b(v.x); o.h[1] = f2b(v.y); o.h[2] = f2b(v.z); o.h[3] = f2b(v.w);
    reinterpret_cast<uint2*>(d)[idx] = o.u;
  } else {  // ---- rope table ----
    const int idx = (bid - 6144) * 256 + t;
    const int j = idx >> 10, w = idx & 1023;
    const float inv = powf(10000.f, -(float)(2 * j) / 32.f);
    float sn, cs;
    sincosf((float)w * inv, &sn, &cs);
    TAB[idx] = make_float2(cs, sn);
  }
}

// ---------------------------------------------------------------------------
// bf16 MFMA GEMM v2: BM=128, BN=64, BK=32, double-buffered LDS 2-phase
// pipeline. grid (W/64, nProj*2, 16), block 256.
// ---------------------------------------------------------------------------
template <bool OUTBF>
__global__ __launch_bounds__(256) void gemm_bt(const u16* __restrict__ Aw,
                                               const u16* __restrict__ Bt,
                                               void* __restrict__ Cc) {
  const int bc = blockIdx.z;
  const int proj = blockIdx.y >> 1;
  const int g0 = (blockIdx.y & 1) * 128;
  const int w0 = blockIdx.x * 64;
  const int t = threadIdx.x;
  const int ln = t & 63, wid = t >> 6;
  const int lr = ln & 15, lk = (ln >> 4) * 8;
  const int wr = wid >> 1, wc = wid & 1;

  const u16* Ab = Aw + (size_t)proj * C * F * F + (size_t)(bc & 7) * F * F;
  const u16* Bb = Bt + (size_t)bc * W * F;

  __shared__ u16 sA[2][8 * 512];
  __shared__ u16 sB[2][4 * 512];

  const u16* ga0 = Ab + (size_t)(g0 + (wid * 2 + 0) * 16 + lr) * F + lk;
  const u16* ga1 = Ab + (size_t)(g0 + (wid * 2 + 1) * 16 + lr) * F + lk;
  const u16* gb0 = Bb + (size_t)(w0 + wid * 16 + lr) * F + lk;

  f32x4 acc[4][2] = {};

  gload16(ga0, &sA[0][(wid * 2 + 0) * 512], ln);
  gload16(ga1, &sA[0][(wid * 2 + 1) * 512], ln);
  gload16(gb0, &sB[0][wid * 512], ln);
  __syncthreads();

  for (int s = 0; s < 8; ++s) {  // 8 steps of BK=32
    const int cur = s & 1;
    if (s < 7) {
      const int h1 = (s + 1) * 32;
      gload16(ga0 + h1, &sA[cur ^ 1][(wid * 2 + 0) * 512], ln);
      gload16(ga1 + h1, &sA[cur ^ 1][(wid * 2 + 1) * 512], ln);
      gload16(gb0 + h1, &sB[cur ^ 1][wid * 512], ln);
    }
    sh8 af[4], bfr[2];
#pragma unroll
    for (int mi = 0; mi < 4; ++mi)
      af[mi] = *(const sh8*)&sA[cur][((wr * 4 + mi) * 64 + ln) * 8];
#pragma unroll
    for (int ni = 0; ni < 2; ++ni)
      bfr[ni] = *(const sh8*)&sB[cur][((wc * 2 + ni) * 64 + ln) * 8];
#pragma unroll
    for (int mi = 0; mi < 4; ++mi)
#pragma unroll
      for (int ni = 0; ni < 2; ++ni)
        acc[mi][ni] = mfma32(af[mi], bfr[ni], acc[mi][ni]);
    __syncthreads();
  }

  const int lq = ln >> 4;
  const size_t cbase = ((size_t)proj * B * C + bc) * F * W;
  if (OUTBF) {
    u16* Cb = (u16*)Cc + cbase;
#pragma unroll
    for (int mi = 0; mi < 4; ++mi)
#pragma unroll
      for (int ni = 0; ni < 2; ++ni)
#pragma unroll
        for (int r = 0; r < 4; ++r)
          Cb[(size_t)(g0 + wr * 64 + mi * 16 + lq * 4 + r) * W + w0 + wc * 32 + ni * 16 + lr] =
              f2b(acc[mi][ni][r]);
  } else {
    float* Cb = (float*)Cc + cbase;
#pragma unroll
    for (int mi = 0; mi < 4; ++mi)
#pragma unroll
      for (int ni = 0; ni < 2; ++ni)
#pragma unroll
        for (int r = 0; r < 4; ++r)
          Cb[(size_t)(g0 + wr * 64 + mi * 16 + lq * 4 + r) * W + w0 + wc * 32 + ni * 16 + lr] =
              acc[mi][ni][r];
  }
}

// ---------------------------------------------------------------------------
// conv1x3 + fused RoPE. K projection written u32-interleaved [bc][pair][w].
// grid (F/2, 3*B), block 256.
// ---------------------------------------------------------------------------
__global__ __launch_bounds__(256) void conv2(const u16* __restrict__ IN,
                                             const float* __restrict__ CWq,
                                             const float* __restrict__ CWk,
                                             const float* __restrict__ CWv,
                                             const float* __restrict__ TAB,
                                             u16* __restrict__ OUT) {
  const int f2 = blockIdx.x;
  const int z = blockIdx.y;
  const int proj = z >> 1, b = z & 1;
  const float* CW = proj == 0 ? CWq : proj == 1 ? CWk : CWv;
  const size_t NB = (size_t)B * C * F * W;
  const u16* INp = IN + (size_t)proj * NB;
  u16* OUTp = OUT + (size_t)proj * NB;
  const int do_rope = (proj < 2);
  const float scale = (proj == 0) ? QSCALE : 1.0f;
  const int f0 = f2 * 2;
  const int t = threadIdx.x;

  __shared__ u16 s[2][C][1040];
  __shared__ float cw[C][C][3];
  if (t < C * C * 3) ((float*)cw)[t] = CW[t];
  if (t < 16) {
    const int fi = t >> 3, c2 = t & 7;
    s[fi][c2][7] = 0;
    s[fi][c2][1032] = 0;
  }
  {
    const int l = t & 127, rsel = t >> 7;
#pragma unroll
    for (int p = 0; p < 8; ++p) {
      const int row = p * 2 + rsel;
      const int fi = row >> 3, c2 = row & 7;
      const u16* src = INp + ((size_t)(b * C + c2) * F + f0 + fi) * W + l * 8;
      *(sh8*)&s[fi][c2][8 + l * 8] = *(const sh8*)src;
    }
  }
  __syncthreads();

  float acc[2][C][4] = {};
#pragma unroll
  for (int c = 0; c < C; ++c) {
    float v[2][6];
#pragma unroll
    for (int fi = 0; fi < 2; ++fi) {
      const u32* r32 = (const u32*)&s[fi][c][0];
      const u32 r0 = r32[2 * t + 3];
      const u32 r1 = r32[2 * t + 4];
      const u32 r2 = r32[2 * t + 5];
      const u32 r3 = r32[2 * t + 6];
      v[fi][0] = ubits(r0 & 0xffff0000u);
      v[fi][1] = ubits(r1 << 16);
      v[fi][2] = ubits(r1 & 0xffff0000u);
      v[fi][3] = ubits(r2 << 16);
      v[fi][4] = ubits(r2 & 0xffff0000u);
      v[fi][5] = ubits(r3 << 16);
    }
#pragma unroll
    for (int d = 0; d < C; ++d) {
      const float c0 = cw[d][c][0], c1 = cw[d][c][1], c2_ = cw[d][c][2];
#pragma unroll
      for (int fi = 0; fi < 2; ++fi)
#pragma unroll
        for (int o = 0; o < 4; ++o)
          acc[fi][d][o] += v[fi][o] * c0 + v[fi][o + 1] * c1 + v[fi][o + 2] * c2_;
    }
  }

  float cs[4] = {1.f, 1.f, 1.f, 1.f}, sn[4] = {0.f, 0.f, 0.f, 0.f};
  if (do_rope) {
    const int j = f2 & 15;
    // TAB entries are float2: element stride is 2 floats per (cos,sin) entry!
    const float4* tp = (const float4*)(TAB + (size_t)(j * 1024 + 4 * t) * 2);
    const float4 A0 = tp[0], A1 = tp[1];
    cs[0] = A0.x; sn[0] = A0.y; cs[1] = A0.z; sn[1] = A0.w;
    cs[2] = A1.x; sn[2] = A1.y; cs[3] = A1.z; sn[3] = A1.w;
  }

#pragma unroll
  for (int d = 0; d < C; ++d) {
    sh4 pk0, pk1;
    uint4 pkI;
    u32* pkIa = (u32*)&pkI;
#pragma unroll
    for (int o = 0; o < 4; ++o) {
      const float a0 = acc[0][d][o], a1 = acc[1][d][o];
      float o0 = a0, o1 = a1;
      if (do_rope) { o0 = a0 * cs[o] - a1 * sn[o]; o1 = a1 * cs[o] + a0 * sn[o]; }
      const u16 e0 = f2b(o0 * scale), e1 = f2b(o1 * scale);
      pk0[o] = (short)e0;
      pk1[o] = (short)e1;
      pkIa[o] = (u32)e0 | ((u32)e1 << 16);
    }
    if (proj == 1) {  // K: u32-interleaved [bc][pair][w]
      *(uint4*)((u32*)OUTp + ((size_t)(b * C + d) * (F / 2) + f2) * W + 4 * t) = pkI;
    } else {
      u16* dst = OUTp + ((size_t)(b * C + d) * F + f0) * W + 4 * t;
      *(sh4*)dst = pk0;
      *(sh4*)(dst + W) = pk1;
    }
  }
}

// ---------------------------------------------------------------------------
// MFMA flash attention v7: FULL K/V in LDS (145 KB), ZERO barriers and ZERO
// global loads in the main loop. 16 waves; each wave owns 16 q-rows and runs
// its 16-tile loop independently. Per-tile math and accumulation order
// identical to v6b (bit-identical output). grid (W/256, NH, B*C), block 1024.
// ---------------------------------------------------------------------------
__global__ __launch_bounds__(1024) void attn_bf(const u16* __restrict__ Q,
                                                const u16* __restrict__ KI,
                                                const u16* __restrict__ Vv,
                                                u16* __restrict__ OT) {
  const int bc = blockIdx.z, n = blockIdx.y, q0 = blockIdx.x * 256;
  const int t = threadIdx.x, ln = t & 63, wid = t >> 6;  // 16 waves
  const int lc = ln & 15, g4 = (ln >> 4) * 4;
  const int dq = (ln >> 4) * 8;
  const size_t base = ((size_t)bc * F + n * HD) * W;

  __shared__ u16 Kl[1024 * 40];  // [key][d], stride 40 (80 B rows, 16B-aligned)
  __shared__ u16 Vl[32 * 1036];  // [d][key], stride 1036 (conflict-free b64)

  // ---- stage ALL 1024 keys of K and V (32 coalesced u32 loads/thread) ----
  {
    const u32* gKI = (const u32*)KI + ((size_t)bc * (F / 2) + n * 16) * W;
    const u32* gVI = (const u32*)(Vv + base);
#pragma unroll
    for (int i = 0; i < 16; ++i) {
      const int idx = t + i * 1024;
      const int pl = idx >> 10, key = idx & 1023;  // dim-pair, key
      *(u32*)&Kl[key * 40 + pl * 2] = gKI[(size_t)pl * W + key];
    }
#pragma unroll
    for (int i = 0; i < 16; ++i) {
      const int idx = t + i * 1024;
      const int d = idx >> 9, kp = idx & 511;  // dim, key-pair
      *(u32*)&Vl[d * 1036 + kp * 2] = gVI[(size_t)d * (W / 2) + kp];
    }
  }

  const int qw = q0 + wid * 16 + lc;
  sh8 qf;
#pragma unroll
  for (int j = 0; j < 8; ++j) qf[j] = (short)Q[base + (size_t)(dq + j) * W + qw];

  const sh4 ones = {0x3F80, 0x3F80, 0x3F80, 0x3F80};  // bf16 1.0 x4
  f32x4 o0 = {0.f, 0.f, 0.f, 0.f}, o1 = {0.f, 0.f, 0.f, 0.f};
  f32x4 dn = {0.f, 0.f, 0.f, 0.f};

  __syncthreads();  // the ONLY barrier

  for (int tile = 0; tile < 16; ++tile) {
    const int k0 = tile * 64;

    f32x4 sf[4];
    __builtin_amdgcn_s_setprio(1);
#pragma unroll
    for (int kh = 0; kh < 4; ++kh) {
      const sh8 kf = *(const sh8*)&Kl[(k0 + kh * 16 + lc) * 40 + dq];
      f32x4 z = {0.f, 0.f, 0.f, 0.f};
      sf[kh] = mfma32(kf, qf, z);
    }
    __builtin_amdgcn_s_setprio(0);

    sh4 pb[4];
#pragma unroll
    for (int kh = 0; kh < 4; ++kh) {
      const float p0 = fexp2(sf[kh][0]);
      const float p1 = fexp2(sf[kh][1]);
      const float p2 = fexp2(sf[kh][2]);
      const float p3 = fexp2(sf[kh][3]);
      pb[kh] = pack4(p0, p1, p2, p3);
    }

    __builtin_amdgcn_s_setprio(1);
#pragma unroll
    for (int kh = 0; kh < 4; ++kh) {
      const sh4 vf0 = *(const sh4*)&Vl[lc * 1036 + k0 + kh * 16 + g4];
      const sh4 vf1 = *(const sh4*)&Vl[(16 + lc) * 1036 + k0 + kh * 16 + g4];
      o0 = mfma16(pb[kh], vf0, o0);
      o1 = mfma16(pb[kh], vf1, o1);
      dn = mfma16(pb[kh], ones, dn);  // denominator: row-sum of P
    }
    __builtin_amdgcn_s_setprio(0);
  }

  // epilogue: OT[bc][w=qrow][f=n*32+lc(+16)], bf16
  const size_t obase = (size_t)bc * W * F + n * HD;
#pragma unroll
  for (int r = 0; r < 4; ++r) {
    const float inv = 1.f / dn[r];
    const int qrow = q0 + wid * 16 + g4 + r;
    OT[obase + (size_t)qrow * F + lc] = f2b(o0[r] * inv);
    OT[obase + (size_t)qrow * F + 16 + lc] = f2b(o1[r] * inv);
  }
}

// ---------------------------------------------------------------------------
// Channel mix v2b (bf16 in/out; input already [b*8+c][w][f]).
// grid (W/4, B), block 256.
// ---------------------------------------------------------------------------
__global__ __launch_bounds__(256) void chanmix2(const u16* __restrict__ A,
                                                const float* __restrict__ DW,
                                                u16* __restrict__ O1) {
  const int b = blockIdx.y;
  const int w = blockIdx.x * 4 + (threadIdx.x >> 6);
  const int f4 = (threadIdx.x & 63) * 4;
  float dwv[C][C];
#pragma unroll
  for (int d = 0; d < C; ++d)
#pragma unroll
    for (int c = 0; c < C; ++c) dwv[d][c] = DW[d * C + c];

  float av[C][4];
#pragma unroll
  for (int c = 0; c < C; ++c) {
    const uint2 raw = *(const uint2*)&A[(((size_t)(b * C + c)) * W + w) * F + f4];
    av[c][0] = ubits(raw.x << 16);
    av[c][1] = ubits(raw.x & 0xffff0000u);
    av[c][2] = ubits(raw.y << 16);
    av[c][3] = ubits(raw.y & 0xffff0000u);
  }
#pragma unroll
  for (int d = 0; d < C; ++d) {
    float s0 = 0.f, s1 = 0.f, s2 = 0.f, s3 = 0.f;
#pragma unroll
    for (int c = 0; c < C; ++c) {
      s0 += av[c][0] * dwv[d][c];
      s1 += av[c][1] * dwv[d][c];
      s2 += av[c][2] * dwv[d][c];
      s3 += av[c][3] * dwv[d][c];
    }
    *(sh4*)&O1[(((size_t)(b * C + d)) * W + w) * F + f4] = pack4(s0, s1, s2, s3);
  }
}

// ---------------------------------------------------------------------------
extern "C" void kernel_launch(void* const* d_in, const int* in_sizes, int n_in,
                              void* d_out, int out_size, void* d_ws, size_t ws_size,
                              hipStream_t stream) {
  const float* x      = (const float*)d_in[0];
  const float* q_pw   = (const float*)d_in[1];
  const float* q_cw   = (const float*)d_in[2];
  const float* k_pw   = (const float*)d_in[3];
  const float* k_cw   = (const float*)d_in[4];
  const float* v_pw   = (const float*)d_in[5];
  const float* v_cw   = (const float*)d_in[6];
  const float* out_pw = (const float*)d_in[7];
  const float* out_dw = (const float*)d_in[8];

  const size_t NB = (size_t)B * C * F * W;  // 4,194,304
  const size_t CFF = (size_t)C * F * F;     // 524,288

  u16* xt   = (u16*)d_ws;        // NB u16; reused as o1t later
  u16* wqkv = xt + NB;           // 3*CFF u16
  u16* wo   = wqkv + 3 * CFF;    // CFF u16
  u16* t0b  = wo + CFF;          // 3*NB u16 (gemm qkv out); head NB = bf16 attn out (OT)
  u16* qkvb = t0b + 3 * NB;      // 3*NB u16 (conv out; K region u32-interleaved)
  float* tab = (float*)(qkvb + 3 * NB);  // 16*1024 float2 = 131 KB
  u16* obuf = t0b;               // NB u16, layout [bc][w][f] (aliases t0b head)
  u16* o1t  = xt;

  prep<<<4096 + 2048 + 64, 256, 0, stream>>>(
      x, xt, q_pw, k_pw, v_pw, out_pw, wqkv, wqkv + CFF, wqkv + 2 * CFF, wo, (float2*)tab);

  gemm_bt<true><<<dim3(W / 64, 6, B * C), 256, 0, stream>>>(wqkv, xt, t0b);
  conv2<<<dim3(F / 2, 3 * B), 256, 0, stream>>>(t0b, q_cw, k_cw, v_cw, tab, qkvb);

  attn_bf<<<dim3(W / 256, NH, B * C), 1024, 0, stream>>>(qkvb, qkvb + NB, qkvb + 2 * NB, obuf);

  chanmix2<<<dim3(W / 4, B), 256, 0, stream>>>(obuf, out_dw, o1t);
  gemm_bt<false><<<dim3(W / 64, 2, B * C), 256, 0, stream>>>(wo, o1t, d_out);
}

// Round 15
// 98.861 us; speedup vs baseline: 1.1070x; 1.1070x over previous
//
#include <hip/hip_runtime.h>
#include <hip/hip_bf16.h>

#define B 2
#define C 8
#define F 256
#define W 1024
#define NH 8
#define HD 32

typedef float f32x4 __attribute__((ext_vector_type(4)));
typedef short sh8 __attribute__((ext_vector_type(8)));
typedef short sh4 __attribute__((ext_vector_type(4)));
typedef unsigned short u16;
typedef unsigned int u32;

// q pre-scale: (1/sqrt(F)) * log2(e)  so softmax uses native exp2 (v_exp_f32)
#define QSCALE 0.09016843880556021f

// native 2^x: single v_exp_f32
static __device__ __forceinline__ float fexp2(float x) {
#if __has_builtin(__builtin_amdgcn_exp2f)
  return __builtin_amdgcn_exp2f(x);
#else
  return __expf(x * 0.69314718056f);
#endif
}

// fp32 -> bf16 RNE via compiler cast
static __device__ __forceinline__ u16 f2b(float x) {
  union { __hip_bfloat16 h; u16 u; } v;
  v.h = __float2bfloat16(x);
  return v.u;
}
// 4x fp32 -> packed bf16x4 (v_cvt_pk_bf16_f32 pairs)
static __device__ __forceinline__ sh4 pack4(float p0, float p1, float p2, float p3) {
  union { __hip_bfloat162 h2[2]; sh4 s; } u;
  u.h2[0] = __float22bfloat162_rn(make_float2(p0, p1));
  u.h2[1] = __float22bfloat162_rn(make_float2(p2, p3));
  return u.s;
}
static __device__ __forceinline__ float ubits(u32 u) {
  union { u32 u; float f; } v;
  v.u = u;
  return v.f;
}

static __device__ __forceinline__ f32x4 mfma32(sh8 a, sh8 b, f32x4 c) {
  return __builtin_amdgcn_mfma_f32_16x16x32_bf16(a, b, c, 0, 0, 0);
}

static __device__ __forceinline__ f32x4 mfma16(sh4 a, sh4 b, f32x4 c) {
#if __has_builtin(__builtin_amdgcn_mfma_f32_16x16x16bf16_1k)
  return __builtin_amdgcn_mfma_f32_16x16x16bf16_1k(a, b, c, 0, 0, 0);
#else
  f32x4 d;
  asm("v_mfma_f32_16x16x16_bf16 %0, %1, %2, %3" : "=v"(d) : "v"(a), "v"(b), "v"(c));
  return d;
#endif
}

// async global->LDS, 16B/lane. g = PER-LANE source, l = wave-uniform base.
static __device__ __forceinline__ void gload16(const u16* g, u16* l, int ln) {
#if __has_builtin(__builtin_amdgcn_global_load_lds)
  __builtin_amdgcn_global_load_lds((const __attribute__((address_space(1))) void*)g,
                                   (__attribute__((address_space(3))) void*)l, 16, 0, 0);
#else
  *(sh8*)(l + ln * 8) = *(const sh8*)g;
#endif
}

// ---------------------------------------------------------------------------
// prep: fused one-time setup (x transpose / weight cvt / rope table).
// ---------------------------------------------------------------------------
__global__ __launch_bounds__(256) void prep(const float* __restrict__ x, u16* __restrict__ xt,
                                            const float* __restrict__ s0, const float* __restrict__ s1,
                                            const float* __restrict__ s2, const float* __restrict__ s3,
                                            u16* __restrict__ d0, u16* __restrict__ d1,
                                            u16* __restrict__ d2, u16* __restrict__ d3,
                                            float2* __restrict__ TAB) {
  const int bid = blockIdx.x;
  const int t = threadIdx.x;
  if (bid < 4096) {  // ---- x transpose ----
    const int bc = bid >> 8, rem = bid & 255;
    const int h0 = ((rem >> 5) & 7) * 32, w0 = (rem & 31) * 32;
    __shared__ u16 sm[32][34];
    const int a = t & 31, bql = t >> 5;
    const float* src = x + ((size_t)bc * F + h0) * W + w0;
#pragma unroll
    for (int p = 0; p < 4; ++p) {
      const int hl = bql + p * 8;
      sm[a][hl] = f2b(src[(size_t)hl * W + a]);
    }
    __syncthreads();
    u16* dst = xt + ((size_t)bc * W + w0) * F + h0;
#pragma unroll
    for (int p = 0; p < 4; ++p) {
      const int wl = bql + p * 8;
      dst[(size_t)wl * F + a] = sm[wl][a];
    }
  } else if (bid < 6144) {  // ---- weight cvt ----
    const int i = bid - 4096;
    const int which = i >> 9;
    const float* s = which == 0 ? s0 : which == 1 ? s1 : which == 2 ? s2 : s3;
    u16* d = which == 0 ? d0 : which == 1 ? d1 : which == 2 ? d2 : d3;
    const int idx = (i & 511) * 256 + t;
    const float4 v = reinterpret_cast<const float4*>(s)[idx];
    union { u16 h[4]; uint2 u; } o;
    o.h[0] = f2b(v.x); o.h[1] = f2b(v.y); o.h[2] = f2b(v.z); o.h[3] = f2b(v.w);
    reinterpret_cast<uint2*>(d)[idx] = o.u;
  } else {  // ---- rope table ----
    const int idx = (bid - 6144) * 256 + t;
    const int j = idx >> 10, w = idx & 1023;
    const float inv = powf(10000.f, -(float)(2 * j) / 32.f);
    float sn, cs;
    sincosf((float)w * inv, &sn, &cs);
    TAB[idx] = make_float2(cs, sn);
  }
}

// ---------------------------------------------------------------------------
// bf16 MFMA GEMM v2: BM=128, BN=64, BK=32, double-buffered LDS 2-phase
// pipeline. grid (W/64, nProj*2, 16), block 256.
// ---------------------------------------------------------------------------
template <bool OUTBF>
__global__ __launch_bounds__(256) void gemm_bt(const u16* __restrict__ Aw,
                                               const u16* __restrict__ Bt,
                                               void* __restrict__ Cc) {
  const int bc = blockIdx.z;
  const int proj = blockIdx.y >> 1;
  const int g0 = (blockIdx.y & 1) * 128;
  const int w0 = blockIdx.x * 64;
  const int t = threadIdx.x;
  const int ln = t & 63, wid = t >> 6;
  const int lr = ln & 15, lk = (ln >> 4) * 8;
  const int wr = wid >> 1, wc = wid & 1;

  const u16* Ab = Aw + (size_t)proj * C * F * F + (size_t)(bc & 7) * F * F;
  const u16* Bb = Bt + (size_t)bc * W * F;

  __shared__ u16 sA[2][8 * 512];
  __shared__ u16 sB[2][4 * 512];

  const u16* ga0 = Ab + (size_t)(g0 + (wid * 2 + 0) * 16 + lr) * F + lk;
  const u16* ga1 = Ab + (size_t)(g0 + (wid * 2 + 1) * 16 + lr) * F + lk;
  const u16* gb0 = Bb + (size_t)(w0 + wid * 16 + lr) * F + lk;

  f32x4 acc[4][2] = {};

  gload16(ga0, &sA[0][(wid * 2 + 0) * 512], ln);
  gload16(ga1, &sA[0][(wid * 2 + 1) * 512], ln);
  gload16(gb0, &sB[0][wid * 512], ln);
  __syncthreads();

  for (int s = 0; s < 8; ++s) {  // 8 steps of BK=32
    const int cur = s & 1;
    if (s < 7) {
      const int h1 = (s + 1) * 32;
      gload16(ga0 + h1, &sA[cur ^ 1][(wid * 2 + 0) * 512], ln);
      gload16(ga1 + h1, &sA[cur ^ 1][(wid * 2 + 1) * 512], ln);
      gload16(gb0 + h1, &sB[cur ^ 1][wid * 512], ln);
    }
    sh8 af[4], bfr[2];
#pragma unroll
    for (int mi = 0; mi < 4; ++mi)
      af[mi] = *(const sh8*)&sA[cur][((wr * 4 + mi) * 64 + ln) * 8];
#pragma unroll
    for (int ni = 0; ni < 2; ++ni)
      bfr[ni] = *(const sh8*)&sB[cur][((wc * 2 + ni) * 64 + ln) * 8];
#pragma unroll
    for (int mi = 0; mi < 4; ++mi)
#pragma unroll
      for (int ni = 0; ni < 2; ++ni)
        acc[mi][ni] = mfma32(af[mi], bfr[ni], acc[mi][ni]);
    __syncthreads();
  }

  const int lq = ln >> 4;
  const size_t cbase = ((size_t)proj * B * C + bc) * F * W;
  if (OUTBF) {
    u16* Cb = (u16*)Cc + cbase;
#pragma unroll
    for (int mi = 0; mi < 4; ++mi)
#pragma unroll
      for (int ni = 0; ni < 2; ++ni)
#pragma unroll
        for (int r = 0; r < 4; ++r)
          Cb[(size_t)(g0 + wr * 64 + mi * 16 + lq * 4 + r) * W + w0 + wc * 32 + ni * 16 + lr] =
              f2b(acc[mi][ni][r]);
  } else {
    float* Cb = (float*)Cc + cbase;
#pragma unroll
    for (int mi = 0; mi < 4; ++mi)
#pragma unroll
      for (int ni = 0; ni < 2; ++ni)
#pragma unroll
        for (int r = 0; r < 4; ++r)
          Cb[(size_t)(g0 + wr * 64 + mi * 16 + lq * 4 + r) * W + w0 + wc * 32 + ni * 16 + lr] =
              acc[mi][ni][r];
  }
}

// ---------------------------------------------------------------------------
// conv1x3 + fused RoPE. K projection written u32-interleaved [bc][pair][w].
// grid (F/2, 3*B), block 256.
// ---------------------------------------------------------------------------
__global__ __launch_bounds__(256) void conv2(const u16* __restrict__ IN,
                                             const float* __restrict__ CWq,
                                             const float* __restrict__ CWk,
                                             const float* __restrict__ CWv,
                                             const float* __restrict__ TAB,
                                             u16* __restrict__ OUT) {
  const int f2 = blockIdx.x;
  const int z = blockIdx.y;
  const int proj = z >> 1, b = z & 1;
  const float* CW = proj == 0 ? CWq : proj == 1 ? CWk : CWv;
  const size_t NB = (size_t)B * C * F * W;
  const u16* INp = IN + (size_t)proj * NB;
  u16* OUTp = OUT + (size_t)proj * NB;
  const int do_rope = (proj < 2);
  const float scale = (proj == 0) ? QSCALE : 1.0f;
  const int f0 = f2 * 2;
  const int t = threadIdx.x;

  __shared__ u16 s[2][C][1040];
  __shared__ float cw[C][C][3];
  if (t < C * C * 3) ((float*)cw)[t] = CW[t];
  if (t < 16) {
    const int fi = t >> 3, c2 = t & 7;
    s[fi][c2][7] = 0;
    s[fi][c2][1032] = 0;
  }
  {
    const int l = t & 127, rsel = t >> 7;
#pragma unroll
    for (int p = 0; p < 8; ++p) {
      const int row = p * 2 + rsel;
      const int fi = row >> 3, c2 = row & 7;
      const u16* src = INp + ((size_t)(b * C + c2) * F + f0 + fi) * W + l * 8;
      *(sh8*)&s[fi][c2][8 + l * 8] = *(const sh8*)src;
    }
  }
  __syncthreads();

  float acc[2][C][4] = {};
#pragma unroll
  for (int c = 0; c < C; ++c) {
    float v[2][6];
#pragma unroll
    for (int fi = 0; fi < 2; ++fi) {
      const u32* r32 = (const u32*)&s[fi][c][0];
      const u32 r0 = r32[2 * t + 3];
      const u32 r1 = r32[2 * t + 4];
      const u32 r2 = r32[2 * t + 5];
      const u32 r3 = r32[2 * t + 6];
      v[fi][0] = ubits(r0 & 0xffff0000u);
      v[fi][1] = ubits(r1 << 16);
      v[fi][2] = ubits(r1 & 0xffff0000u);
      v[fi][3] = ubits(r2 << 16);
      v[fi][4] = ubits(r2 & 0xffff0000u);
      v[fi][5] = ubits(r3 << 16);
    }
#pragma unroll
    for (int d = 0; d < C; ++d) {
      const float c0 = cw[d][c][0], c1 = cw[d][c][1], c2_ = cw[d][c][2];
#pragma unroll
      for (int fi = 0; fi < 2; ++fi)
#pragma unroll
        for (int o = 0; o < 4; ++o)
          acc[fi][d][o] += v[fi][o] * c0 + v[fi][o + 1] * c1 + v[fi][o + 2] * c2_;
    }
  }

  float cs[4] = {1.f, 1.f, 1.f, 1.f}, sn[4] = {0.f, 0.f, 0.f, 0.f};
  if (do_rope) {
    const int j = f2 & 15;
    // TAB entries are float2: element stride is 2 floats per (cos,sin) entry!
    const float4* tp = (const float4*)(TAB + (size_t)(j * 1024 + 4 * t) * 2);
    const float4 A0 = tp[0], A1 = tp[1];
    cs[0] = A0.x; sn[0] = A0.y; cs[1] = A0.z; sn[1] = A0.w;
    cs[2] = A1.x; sn[2] = A1.y; cs[3] = A1.z; sn[3] = A1.w;
  }

#pragma unroll
  for (int d = 0; d < C; ++d) {
    sh4 pk0, pk1;
    uint4 pkI;
    u32* pkIa = (u32*)&pkI;
#pragma unroll
    for (int o = 0; o < 4; ++o) {
      const float a0 = acc[0][d][o], a1 = acc[1][d][o];
      float o0 = a0, o1 = a1;
      if (do_rope) { o0 = a0 * cs[o] - a1 * sn[o]; o1 = a1 * cs[o] + a0 * sn[o]; }
      const u16 e0 = f2b(o0 * scale), e1 = f2b(o1 * scale);
      pk0[o] = (short)e0;
      pk1[o] = (short)e1;
      pkIa[o] = (u32)e0 | ((u32)e1 << 16);
    }
    if (proj == 1) {  // K: u32-interleaved [bc][pair][w]
      *(uint4*)((u32*)OUTp + ((size_t)(b * C + d) * (F / 2) + f2) * W + 4 * t) = pkI;
    } else {
      u16* dst = OUTp + ((size_t)(b * C + d) * F + f0) * W + 4 * t;
      *(sh4*)dst = pk0;
      *(sh4*)(dst + W) = pk1;
    }
  }
}

// ---------------------------------------------------------------------------
// MFMA flash attention v6c = v6b (R12/R13, proven) + XCD-aware block remap:
// all 4 q-chunks of one (bc,head) get linear ids with equal (id % 8) so they
// land on the SAME XCD -> K/V panels hit in that XCD's L2 instead of being
// re-fetched 4x (T1; FETCH was ~70 MB vs ~24 MB working set).
// grid (W/256, NH, B*C), block 1024.
// ---------------------------------------------------------------------------
__global__ __launch_bounds__(1024) void attn_bf(const u16* __restrict__ Q,
                                                const u16* __restrict__ KI,
                                                const u16* __restrict__ Vv,
                                                u16* __restrict__ OT) {
  // XCD-group decode (bijective on 512 = 8 xcd x 64 slots; mapping heuristic
  // xcd = linear_id % 8 — perf-only, correctness-neutral):
  const int L = blockIdx.x + 4 * (blockIdx.y + 8 * blockIdx.z);
  const int xcd = L & 7, slot = L >> 3;
  const int grp = xcd + 8 * (slot >> 2);       // 0..127 = (bc, n)
  const int bc = grp >> 3, n = grp & 7;
  const int q0 = (slot & 3) * 256;

  const int t = threadIdx.x, ln = t & 63, wid = t >> 6;  // 16 waves
  const int lc = ln & 15, g4 = (ln >> 4) * 4;
  const int dq = (ln >> 4) * 8;
  const size_t base = ((size_t)bc * F + n * HD) * W;

  __shared__ u16 Kl[2][64 * 40];  // [buf][key][d], stride 40
  __shared__ u16 Vl[2][32 * 76];  // [buf][d][key], stride 76

  // K staging: thread t -> key = t&63, dim-pair j = t>>6 (one u32 load)
  const int skey = t & 63, dp = (t >> 6) * 2;
  const u32* gK = (const u32*)KI + ((size_t)bc * (F / 2) + n * 16 + (t >> 6)) * W + skey;
  // V staging: thread t -> d = t>>5, key-pair (t&31)*2 (one 4B load/store)
  const int sd = t >> 5, kc2 = (t & 31) * 2;
  const u16* gV = Vv + base + (size_t)sd * W + kc2;

  const int qw = q0 + wid * 16 + lc;
  sh8 qf;
#pragma unroll
  for (int j = 0; j < 8; ++j) qf[j] = (short)Q[base + (size_t)(dq + j) * W + qw];

  const sh4 ones = {0x3F80, 0x3F80, 0x3F80, 0x3F80};  // bf16 1.0 x4
  f32x4 o0 = {0.f, 0.f, 0.f, 0.f}, o1 = {0.f, 0.f, 0.f, 0.f};
  f32x4 dn = {0.f, 0.f, 0.f, 0.f};

  {  // prologue: stage tile 0 into buf 0
    *(u32*)&Kl[0][skey * 40 + dp] = gK[0];
    *(u32*)&Vl[0][sd * 76 + kc2] = *(const u32*)gV;
  }
  __syncthreads();

  for (int tile = 0; tile < 16; ++tile) {
    const int cur = tile & 1;
    // T14: issue next tile's global loads early, write LDS late
    u32 hvK = 0, hvV = 0;
    if (tile < 15) {
      const int off = (tile + 1) * 64;
      hvK = gK[off];
      hvV = *(const u32*)(gV + off);
    }

    f32x4 sf[4];
    __builtin_amdgcn_s_setprio(1);
#pragma unroll
    for (int kh = 0; kh < 4; ++kh) {
      const sh8 kf = *(const sh8*)&Kl[cur][(kh * 16 + lc) * 40 + dq];
      f32x4 z = {0.f, 0.f, 0.f, 0.f};
      sf[kh] = mfma32(kf, qf, z);
    }
    __builtin_amdgcn_s_setprio(0);

    sh4 pb[4];
#pragma unroll
    for (int kh = 0; kh < 4; ++kh) {
      const float p0 = fexp2(sf[kh][0]);
      const float p1 = fexp2(sf[kh][1]);
      const float p2 = fexp2(sf[kh][2]);
      const float p3 = fexp2(sf[kh][3]);
      pb[kh] = pack4(p0, p1, p2, p3);
    }

    __builtin_amdgcn_s_setprio(1);
#pragma unroll
    for (int kh = 0; kh < 4; ++kh) {
      const sh4 vf0 = *(const sh4*)&Vl[cur][lc * 76 + kh * 16 + g4];
      const sh4 vf1 = *(const sh4*)&Vl[cur][(16 + lc) * 76 + kh * 16 + g4];
      o0 = mfma16(pb[kh], vf0, o0);
      o1 = mfma16(pb[kh], vf1, o1);
      dn = mfma16(pb[kh], ones, dn);  // denominator: row-sum of P
    }
    __builtin_amdgcn_s_setprio(0);

    if (tile < 15) {
      *(u32*)&Kl[cur ^ 1][skey * 40 + dp] = hvK;
      *(u32*)&Vl[cur ^ 1][sd * 76 + kc2] = hvV;
    }
    __syncthreads();
  }

  // epilogue: OT[bc][w=qrow][f=n*32+lc(+16)], bf16
  const size_t obase = (size_t)bc * W * F + n * HD;
#pragma unroll
  for (int r = 0; r < 4; ++r) {
    const float inv = 1.f / dn[r];
    const int qrow = q0 + wid * 16 + g4 + r;
    OT[obase + (size_t)qrow * F + lc] = f2b(o0[r] * inv);
    OT[obase + (size_t)qrow * F + 16 + lc] = f2b(o1[r] * inv);
  }
}

// ---------------------------------------------------------------------------
// Channel mix v2b (bf16 in/out; input already [b*8+c][w][f]).
// grid (W/4, B), block 256.
// ---------------------------------------------------------------------------
__global__ __launch_bounds__(256) void chanmix2(const u16* __restrict__ A,
                                                const float* __restrict__ DW,
                                                u16* __restrict__ O1) {
  const int b = blockIdx.y;
  const int w = blockIdx.x * 4 + (threadIdx.x >> 6);
  const int f4 = (threadIdx.x & 63) * 4;
  float dwv[C][C];
#pragma unroll
  for (int d = 0; d < C; ++d)
#pragma unroll
    for (int c = 0; c < C; ++c) dwv[d][c] = DW[d * C + c];

  float av[C][4];
#pragma unroll
  for (int c = 0; c < C; ++c) {
    const uint2 raw = *(const uint2*)&A[(((size_t)(b * C + c)) * W + w) * F + f4];
    av[c][0] = ubits(raw.x << 16);
    av[c][1] = ubits(raw.x & 0xffff0000u);
    av[c][2] = ubits(raw.y << 16);
    av[c][3] = ubits(raw.y & 0xffff0000u);
  }
#pragma unroll
  for (int d = 0; d < C; ++d) {
    float s0 = 0.f, s1 = 0.f, s2 = 0.f, s3 = 0.f;
#pragma unroll
    for (int c = 0; c < C; ++c) {
      s0 += av[c][0] * dwv[d][c];
      s1 += av[c][1] * dwv[d][c];
      s2 += av[c][2] * dwv[d][c];
      s3 += av[c][3] * dwv[d][c];
    }
    *(sh4*)&O1[(((size_t)(b * C + d)) * W + w) * F + f4] = pack4(s0, s1, s2, s3);
  }
}

// ---------------------------------------------------------------------------
extern "C" void kernel_launch(void* const* d_in, const int* in_sizes, int n_in,
                              void* d_out, int out_size, void* d_ws, size_t ws_size,
                              hipStream_t stream) {
  const float* x      = (const float*)d_in[0];
  const float* q_pw   = (const float*)d_in[1];
  const float* q_cw   = (const float*)d_in[2];
  const float* k_pw   = (const float*)d_in[3];
  const float* k_cw   = (const float*)d_in[4];
  const float* v_pw   = (const float*)d_in[5];
  const float* v_cw   = (const float*)d_in[6];
  const float* out_pw = (const float*)d_in[7];
  const float* out_dw = (const float*)d_in[8];

  const size_t NB = (size_t)B * C * F * W;  // 4,194,304
  const size_t CFF = (size_t)C * F * F;     // 524,288

  u16* xt   = (u16*)d_ws;        // NB u16; reused as o1t later
  u16* wqkv = xt + NB;           // 3*CFF u16
  u16* wo   = wqkv + 3 * CFF;    // CFF u16
  u16* t0b  = wo + CFF;          // 3*NB u16 (gemm qkv out); head NB = bf16 attn out (OT)
  u16* qkvb = t0b + 3 * NB;      // 3*NB u16 (conv out; K region u32-interleaved)
  float* tab = (float*)(qkvb + 3 * NB);  // 16*1024 float2 = 131 KB
  u16* obuf = t0b;               // NB u16, layout [bc][w][f] (aliases t0b head)
  u16* o1t  = xt;

  prep<<<4096 + 2048 + 64, 256, 0, stream>>>(
      x, xt, q_pw, k_pw, v_pw, out_pw, wqkv, wqkv + CFF, wqkv + 2 * CFF, wo, (float2*)tab);

  gemm_bt<true><<<dim3(W / 64, 6, B * C), 256, 0, stream>>>(wqkv, xt, t0b);
  conv2<<<dim3(F / 2, 3 * B), 256, 0, stream>>>(t0b, q_cw, k_cw, v_cw, tab, qkvb);

  attn_bf<<<dim3(W / 256, NH, B * C), 1024, 0, stream>>>(qkvb, qkvb + NB, qkvb + 2 * NB, obuf);

  chanmix2<<<dim3(W / 4, B), 256, 0, stream>>>(obuf, out_dw, o1t);
  gemm_bt<false><<<dim3(W / 64, 2, B * C), 256, 0, stream>>>(wo, o1t, d_out);
}